// Round 1
// baseline (1561.851 us; speedup 1.0000x reference)
//
#include <hip/hip_runtime.h>
#include <hip/hip_bf16.h>
#include <math.h>

#define Bn 32
#define Qn 300
#define Dn 256
#define FFn 1024
#define NHn 8
#define HDn 32
#define SUMPn 12
#define LTOT 8400

// ---------------- elementwise add ----------------
__global__ void add_kernel(const float* __restrict__ a, const float* __restrict__ b,
                           float* __restrict__ out, int n) {
    int i = blockIdx.x * 256 + threadIdx.x;
    if (i < n) out[i] = a[i] + b[i];
}

// ---------------- generic tiled GEMM: C[M,N] = A[M,K] @ W[K,N] + bias ----------------
// ACT: 0 none, 1 relu, 2 sigmoid
template <int ACT>
__global__ void gemm_kernel(const float* __restrict__ A, const float* __restrict__ W,
                            const float* __restrict__ bias, float* __restrict__ C,
                            int M, int N, int K) {
    const int BM = 64, BN = 64, BK = 16;
    __shared__ float As[BK][BM + 1];
    __shared__ float Ws[BK][BN + 1];
    int bm = blockIdx.y * BM, bn = blockIdx.x * BN;
    int t = threadIdx.x;                 // 0..255
    int tm = (t >> 4) << 2;              // 0,4,...,60
    int tn = (t & 15) << 2;              // 0,4,...,60
    float acc[4][4] = {};
    for (int k0 = 0; k0 < K; k0 += BK) {
#pragma unroll
        for (int i = 0; i < 4; i++) {    // A tile: 64x16
            int idx = t + i * 256;
            int m = idx >> 4, kk = idx & 15;
            int gm = bm + m;
            float v = 0.f;
            if (gm < M) v = A[(size_t)gm * K + (k0 + kk)];
            As[kk][m] = v;
        }
#pragma unroll
        for (int i = 0; i < 4; i++) {    // W tile: 16x64
            int idx = t + i * 256;
            int kk = idx >> 6, n = idx & 63;
            int gn = bn + n;
            float v = 0.f;
            if (gn < N) v = W[(size_t)(k0 + kk) * N + gn];
            Ws[kk][n] = v;
        }
        __syncthreads();
#pragma unroll
        for (int kk = 0; kk < BK; kk++) {
            float a0 = As[kk][tm + 0], a1 = As[kk][tm + 1], a2 = As[kk][tm + 2], a3 = As[kk][tm + 3];
            float b0 = Ws[kk][tn + 0], b1 = Ws[kk][tn + 1], b2 = Ws[kk][tn + 2], b3 = Ws[kk][tn + 3];
            acc[0][0] += a0 * b0; acc[0][1] += a0 * b1; acc[0][2] += a0 * b2; acc[0][3] += a0 * b3;
            acc[1][0] += a1 * b0; acc[1][1] += a1 * b1; acc[1][2] += a1 * b2; acc[1][3] += a1 * b3;
            acc[2][0] += a2 * b0; acc[2][1] += a2 * b1; acc[2][2] += a2 * b2; acc[2][3] += a2 * b3;
            acc[3][0] += a3 * b0; acc[3][1] += a3 * b1; acc[3][2] += a3 * b2; acc[3][3] += a3 * b3;
        }
        __syncthreads();
    }
#pragma unroll
    for (int i = 0; i < 4; i++) {
        int gm = bm + tm + i;
        if (gm >= M) continue;
#pragma unroll
        for (int j = 0; j < 4; j++) {
            int gn = bn + tn + j;
            if (gn >= N) continue;
            float v = acc[i][j] + bias[gn];
            if (ACT == 1) v = fmaxf(v, 0.f);
            if (ACT == 2) v = 1.f / (1.f + __expf(-v));
            C[(size_t)gm * N + gn] = v;
        }
    }
}

// ---------------- attention scores: scores[bh,q,k] = q.k / sqrt(HD) ----------------
__global__ void scores_kernel(const float* __restrict__ q, const float* __restrict__ k,
                              float* __restrict__ scores) {
    int bh = blockIdx.z;
    int b = bh >> 3, h = bh & 7;
    int q0 = blockIdx.y * 16, k0 = blockIdx.x * 16;
    __shared__ float qs[16][HDn];
    __shared__ float ks[16][HDn];
    int t = threadIdx.y * 16 + threadIdx.x;
#pragma unroll
    for (int i = 0; i < 2; i++) {
        int idx = t + i * 256;
        int r = idx >> 5, d = idx & 31;
        int gq = q0 + r;
        qs[r][d] = (gq < Qn) ? q[(((size_t)b * Qn + gq) * NHn + h) * HDn + d] : 0.f;
        int gk = k0 + r;
        ks[r][d] = (gk < Qn) ? k[(((size_t)b * Qn + gk) * NHn + h) * HDn + d] : 0.f;
    }
    __syncthreads();
    int qi = q0 + threadIdx.y, ki = k0 + threadIdx.x;
    if (qi < Qn && ki < Qn) {
        float s = 0.f;
#pragma unroll
        for (int d = 0; d < HDn; d++) s += qs[threadIdx.y][d] * ks[threadIdx.x][d];
        scores[((size_t)bh * Qn + qi) * Qn + ki] = s * 0.17677669529663687f;
    }
}

// ---------------- softmax over 300, one wave per row ----------------
__global__ void softmax_rows_kernel(float* __restrict__ s, int nrows) {
    int wid = threadIdx.x >> 6, lane = threadIdx.x & 63;
    int row = blockIdx.x * 4 + wid;
    if (row >= nrows) return;
    float* p = s + (size_t)row * Qn;
    float vals[5];
    float mx = -1e30f;
#pragma unroll
    for (int i = 0; i < 5; i++) {
        int j = lane + i * 64;
        vals[i] = (j < Qn) ? p[j] : -1e30f;
        mx = fmaxf(mx, vals[i]);
    }
#pragma unroll
    for (int o = 32; o > 0; o >>= 1) mx = fmaxf(mx, __shfl_xor(mx, o));
    float sum = 0.f;
#pragma unroll
    for (int i = 0; i < 5; i++) {
        int j = lane + i * 64;
        vals[i] = (j < Qn) ? __expf(vals[i] - mx) : 0.f;
        sum += vals[i];
    }
#pragma unroll
    for (int o = 32; o > 0; o >>= 1) sum += __shfl_xor(sum, o);
    float inv = 1.f / sum;
#pragma unroll
    for (int i = 0; i < 5; i++) {
        int j = lane + i * 64;
        if (j < Qn) p[j] = vals[i] * inv;
    }
}

// ---------------- ctx[b,q,h,d] = sum_k attn[bh,q,k] * v[b,k,h,d] ----------------
__global__ void ctx_kernel(const float* __restrict__ attn, const float* __restrict__ v,
                           float* __restrict__ ctx) {
    int bh = blockIdx.x;
    int b = bh >> 3, h = bh & 7;
    int q = blockIdx.y * 8 + threadIdx.y;
    int d = threadIdx.x;
    if (q >= Qn) return;
    const float* arow = attn + ((size_t)bh * Qn + q) * Qn;
    float acc = 0.f;
    for (int k = 0; k < Qn; k++) {
        acc += arow[k] * v[(((size_t)b * Qn + k) * NHn + h) * HDn + d];
    }
    ctx[(((size_t)b * Qn + q) * NHn + h) * HDn + d] = acc;
}

// ---------------- block reduction helper ----------------
__device__ __forceinline__ float block_sum_256(float v, float* red) {
#pragma unroll
    for (int o = 32; o > 0; o >>= 1) v += __shfl_down(v, o);
    int lane = threadIdx.x & 63, w = threadIdx.x >> 6;
    if (lane == 0) red[w] = v;
    __syncthreads();
    float s = red[0] + red[1] + red[2] + red[3];
    __syncthreads();
    return s;
}

// ---------------- LN(a+b) ----------------
__global__ void ln_residual_kernel(const float* __restrict__ a, const float* __restrict__ b,
                                   const float* __restrict__ g, const float* __restrict__ be,
                                   float* __restrict__ out) {
    __shared__ float red[4];
    int row = blockIdx.x, c = threadIdx.x;
    float x = a[(size_t)row * Dn + c] + b[(size_t)row * Dn + c];
    float m = block_sum_256(x, red) * (1.f / Dn);
    float d = x - m;
    float var = block_sum_256(d * d, red) * (1.f / Dn);
    out[(size_t)row * Dn + c] = d * rsqrtf(var + 1e-5f) * g[c] + be[c];
}

// ---------------- softmax over 12 points per (b,q,h) ----------------
__global__ void aw_softmax_kernel(float* __restrict__ aw, int n) {
    int i = blockIdx.x * 256 + threadIdx.x;
    if (i >= n) return;
    float* p = aw + (size_t)i * SUMPn;
    float v[SUMPn];
    float mx = -1e30f;
#pragma unroll
    for (int j = 0; j < SUMPn; j++) { v[j] = p[j]; mx = fmaxf(mx, v[j]); }
    float sum = 0.f;
#pragma unroll
    for (int j = 0; j < SUMPn; j++) { v[j] = __expf(v[j] - mx); sum += v[j]; }
    float inv = 1.f / sum;
#pragma unroll
    for (int j = 0; j < SUMPn; j++) p[j] = v[j] * inv;
}

// ---------------- deformable sampling ----------------
__device__ __forceinline__ float samp(const float* __restrict__ enc, int b, int s0, int H, int W,
                                      int h, int d, int yi, int xi) {
    bool valid = (xi >= 0) && (xi < W) && (yi >= 0) && (yi < H);
    int xc = min(max(xi, 0), W - 1);
    int yc = min(max(yi, 0), H - 1);
    size_t idx = (size_t)b * LTOT + s0 + yc * W + xc;
    float v = enc[(idx * NHn + h) * HDn + d];
    return valid ? v : 0.f;
}

__global__ void deform_kernel(const float* __restrict__ enc, const float* __restrict__ ref,
                              const float* __restrict__ off, const float* __restrict__ aw,
                              float* __restrict__ ca) {
    int i = blockIdx.x * 256 + threadIdx.x;  // < B*Q*NH*HD
    int d = i & (HDn - 1);
    int h = (i >> 5) & (NHn - 1);
    int bq = i >> 8;
    const float* r4 = ref + (size_t)bq * 4;
    int b = bq / Qn;
    float rx = r4[0], ry = r4[1], rw = r4[2] * 0.5f, rh = r4[3] * 0.5f;
    const float* offp = off + ((size_t)bq * NHn + h) * SUMPn * 2;
    const float* awp = aw + ((size_t)bq * NHn + h) * SUMPn;
    const int Hs[3] = {80, 40, 20};
    const int Ws_[3] = {80, 40, 20};
    const int S0[3] = {0, 6400, 8000};
    float acc = 0.f;
#pragma unroll
    for (int l = 0; l < 3; l++) {
        int H = Hs[l], W = Ws_[l], s0 = S0[l];
#pragma unroll
        for (int p = 0; p < 4; p++) {
            int pt = l * 4 + p;
            float lx_ = rx + offp[pt * 2 + 0] * 0.25f * rw;
            float ly_ = ry + offp[pt * 2 + 1] * 0.25f * rh;
            float x = lx_ * W - 0.5f;
            float y = ly_ * H - 0.5f;
            float x0f = floorf(x), y0f = floorf(y);
            float fx = x - x0f, fy = y - y0f;
            int x0 = (int)x0f, y0 = (int)y0f;
            float w = awp[pt];
            float v00 = samp(enc, b, s0, H, W, h, d, y0, x0);
            float v01 = samp(enc, b, s0, H, W, h, d, y0, x0 + 1);
            float v10 = samp(enc, b, s0, H, W, h, d, y0 + 1, x0);
            float v11 = samp(enc, b, s0, H, W, h, d, y0 + 1, x0 + 1);
            float sv = (v00 * (1.f - fx) + v01 * fx) * (1.f - fy) +
                       (v10 * (1.f - fx) + v11 * fx) * fy;
            acc += w * sv;
        }
    }
    ca[i] = acc;
}

// ---------------- concat [res | ca] ----------------
__global__ void concat_kernel(const float* __restrict__ a, const float* __restrict__ b,
                              float* __restrict__ out, int n) {
    int i = blockIdx.x * 256 + threadIdx.x;
    if (i >= n) return;
    int row = i >> 9;       // /512
    int c = i & 511;
    out[i] = (c < Dn) ? a[(size_t)row * Dn + c] : b[(size_t)row * Dn + (c - Dn)];
}

// ---------------- gated combine + LN ----------------
__global__ void gate_ln_kernel(const float* __restrict__ gates, const float* __restrict__ res,
                               const float* __restrict__ ca, const float* __restrict__ g,
                               const float* __restrict__ be, float* __restrict__ out) {
    __shared__ float red[4];
    int row = blockIdx.x, c = threadIdx.x;
    float g1 = gates[(size_t)row * 2 * Dn + c];
    float g2 = gates[(size_t)row * 2 * Dn + Dn + c];
    float x = g1 * res[(size_t)row * Dn + c] + g2 * ca[(size_t)row * Dn + c];
    float m = block_sum_256(x, red) * (1.f / Dn);
    float d = x - m;
    float var = block_sum_256(d * d, red) * (1.f / Dn);
    out[(size_t)row * Dn + c] = d * rsqrtf(var + 1e-5f) * g[c] + be[c];
}

// ---------------- final: LN(clamp(h2 + ffn)) ----------------
__global__ void final_ln_kernel(const float* __restrict__ h2, const float* __restrict__ ffn,
                                const float* __restrict__ g, const float* __restrict__ be,
                                float* __restrict__ out) {
    __shared__ float red[4];
    int row = blockIdx.x, c = threadIdx.x;
    float x = h2[(size_t)row * Dn + c] + ffn[(size_t)row * Dn + c];
    const float CL = 3.4028232e38f;
    x = fminf(fmaxf(x, -CL), CL);
    float m = block_sum_256(x, red) * (1.f / Dn);
    float d = x - m;
    float var = block_sum_256(d * d, red) * (1.f / Dn);
    out[(size_t)row * Dn + c] = d * rsqrtf(var + 1e-5f) * g[c] + be[c];
}

extern "C" void kernel_launch(void* const* d_in, const int* in_sizes, int n_in,
                              void* d_out, int out_size, void* d_ws, size_t ws_size,
                              hipStream_t stream) {
    const float* hs    = (const float*)d_in[0];
    const float* pos   = (const float*)d_in[1];
    const float* ref   = (const float*)d_in[2];
    const float* enc   = (const float*)d_in[3];
    const float* Wq    = (const float*)d_in[4];
    const float* bq    = (const float*)d_in[5];
    const float* Wk    = (const float*)d_in[6];
    const float* bk    = (const float*)d_in[7];
    const float* Wv    = (const float*)d_in[8];
    const float* bv    = (const float*)d_in[9];
    const float* Wo    = (const float*)d_in[10];
    const float* bo    = (const float*)d_in[11];
    const float* ln1g  = (const float*)d_in[12];
    const float* ln1b  = (const float*)d_in[13];
    const float* Woff  = (const float*)d_in[14];
    const float* boff  = (const float*)d_in[15];
    const float* Wattn = (const float*)d_in[16];
    const float* battn = (const float*)d_in[17];
    const float* Wgate = (const float*)d_in[18];
    const float* bgate = (const float*)d_in[19];
    const float* glng  = (const float*)d_in[20];
    const float* glnb  = (const float*)d_in[21];
    const float* Wfc1  = (const float*)d_in[22];
    const float* bfc1  = (const float*)d_in[23];
    const float* Wfc2  = (const float*)d_in[24];
    const float* bfc2  = (const float*)d_in[25];
    const float* ln2g  = (const float*)d_in[26];
    const float* ln2b  = (const float*)d_in[27];

    float* out = (float*)d_out;
    float* ws = (float*)d_ws;

    const size_t A = (size_t)Bn * Qn * Dn;          // 2,457,600
    const size_t S = (size_t)Bn * NHn * Qn * Qn;    // 23,040,000
    const size_t NOFF = (size_t)Bn * Qn * NHn * SUMPn * 2;  // 1,843,200
    const size_t NAW  = (size_t)Bn * Qn * NHn * SUMPn;      //   921,600

    float* qkin   = ws;
    float* qb     = ws + A;
    float* kb     = ws + 2 * A;
    float* vb     = ws + 3 * A;
    float* scores = ws + 4 * A;
    float* hb     = ws + 4 * A + S;
    float* qc     = ws + 5 * A + S;
    float* offb   = ws + 6 * A + S;
    float* awb    = offb + NOFF;
    // reuse
    float* ctx     = qkin;           // qkin dead after q,k,v
    float* tmp     = kb;             // k dead after scores
    float* ca      = qb;             // q dead after scores
    float* concatb = scores;         // 2A
    float* gates   = scores + 2 * A; // 2A
    float* h2      = kb;             // tmp dead after ln1
    float* midb    = scores;         // 4A, concat+gates dead
    float* ffnout  = vb;             // v dead after ctx

    const int M = Bn * Qn;  // 9600

    // 1. qkin = hs + pos
    add_kernel<<<dim3((A + 255) / 256), 256, 0, stream>>>(hs, pos, qkin, (int)A);
    // 2-4. q,k,v projections
    gemm_kernel<0><<<dim3(4, 150), 256, 0, stream>>>(qkin, Wq, bq, qb, M, Dn, Dn);
    gemm_kernel<0><<<dim3(4, 150), 256, 0, stream>>>(qkin, Wk, bk, kb, M, Dn, Dn);
    gemm_kernel<0><<<dim3(4, 150), 256, 0, stream>>>(hs, Wv, bv, vb, M, Dn, Dn);
    // 5. scores
    scores_kernel<<<dim3(19, 19, Bn * NHn), dim3(16, 16), 0, stream>>>(qb, kb, scores);
    // 6. softmax over keys
    softmax_rows_kernel<<<dim3((Bn * NHn * Qn + 3) / 4), 256, 0, stream>>>(scores, Bn * NHn * Qn);
    // 7. ctx
    ctx_kernel<<<dim3(Bn * NHn, (Qn + 7) / 8), dim3(32, 8), 0, stream>>>(scores, vb, ctx);
    // 8. out proj
    gemm_kernel<0><<<dim3(4, 150), 256, 0, stream>>>(ctx, Wo, bo, tmp, M, Dn, Dn);
    // 9. h = LN(hs + tmp)
    ln_residual_kernel<<<dim3(M), 256, 0, stream>>>(hs, tmp, ln1g, ln1b, hb);
    // 10. qc = h + pos
    add_kernel<<<dim3((A + 255) / 256), 256, 0, stream>>>(hb, pos, qc, (int)A);
    // 11. offsets
    gemm_kernel<0><<<dim3(3, 150), 256, 0, stream>>>(qc, Woff, boff, offb, M, NHn * SUMPn * 2, Dn);
    // 12. attn weights logits
    gemm_kernel<0><<<dim3(2, 150), 256, 0, stream>>>(qc, Wattn, battn, awb, M, NHn * SUMPn, Dn);
    // 13. softmax over 12 pts
    aw_softmax_kernel<<<dim3((Bn * Qn * NHn + 255) / 256), 256, 0, stream>>>(awb, Bn * Qn * NHn);
    // 14. deformable sampling
    deform_kernel<<<dim3((int)(A / 256)), 256, 0, stream>>>(enc, ref, offb, awb, ca);
    // 15. concat [h | ca]
    concat_kernel<<<dim3((int)(2 * A / 256)), 256, 0, stream>>>(hb, ca, concatb, (int)(2 * A));
    // 16. gates = sigmoid(concat @ Wgate + bgate)
    gemm_kernel<2><<<dim3(8, 150), 256, 0, stream>>>(concatb, Wgate, bgate, gates, M, 2 * Dn, 2 * Dn);
    // 17. h2 = LN(g1*h + g2*ca)
    gate_ln_kernel<<<dim3(M), 256, 0, stream>>>(gates, hb, ca, glng, glnb, h2);
    // 18. mid = relu(h2 @ Wfc1 + bfc1)
    gemm_kernel<1><<<dim3(16, 150), 256, 0, stream>>>(h2, Wfc1, bfc1, midb, M, FFn, Dn);
    // 19. ffnout = mid @ Wfc2 + bfc2
    gemm_kernel<0><<<dim3(4, 150), 256, 0, stream>>>(midb, Wfc2, bfc2, ffnout, M, Dn, FFn);
    // 20. out = LN(clamp(h2 + ffnout))
    final_ln_kernel<<<dim3(M), 256, 0, stream>>>(h2, ffnout, ln2g, ln2b, out);
}